// Round 29
// baseline (120.514 us; speedup 1.0000x reference)
//
#include <hip/hip_runtime.h>
#include <hip/hip_bf16.h>

#define N_NODES 50000
#define E_EDGES 600000
#define F_IN    256
#define HC1     128   // 4 heads * 32
#define F_OUT   64
#define NBKT    196   // ceil(N_NODES/256) coarse dst-buckets
#define BMAX    6144  // per-bucket capacity (mean 3316, sigma ~58)
#define APB     8192  // edges per bappend chunk
#define NAB     80    // ceil((E+N)/APB)
#define GB1     3125  // gemm1 tile blocks = N/16 (exact)
#define NPACK   (F_IN * HC1 + HC1 * F_OUT)   // 40960

typedef __bf16 bf16x8 __attribute__((ext_vector_type(8)));
typedef __bf16 bf16x4 __attribute__((ext_vector_type(4)));
typedef float  f32x4  __attribute__((ext_vector_type(4)));

__device__ __forceinline__ float lrelu(float x) { return x > 0.f ? x : 0.2f * x; }
__device__ __forceinline__ float bfhi(unsigned v) { return __uint_as_float(v & 0xffff0000u); }
__device__ __forceinline__ float bflo(unsigned v) { return __uint_as_float(v << 16); }

// -------------------- init: zero bucket cursors + pack W (fused) --------------

__global__ __launch_bounds__(256) void init_kernel(const float* __restrict__ W1,
                                                   const float* __restrict__ W2,
                                                   __bf16* __restrict__ hi1, __bf16* __restrict__ lo1,
                                                   __bf16* __restrict__ hi2, __bf16* __restrict__ lo2,
                                                   int* __restrict__ bcur) {
    if (blockIdx.x == 0) {
        if (threadIdx.x < NBKT) bcur[threadIdx.x] = 0;
        return;
    }
    int tid = (blockIdx.x - 1) * 256 + threadIdx.x;
    if (tid >= NPACK) return;
    if (tid < F_IN * HC1) {
        int t = tid;
        int j = t & 7, l = (t >> 3) & 63, kt = (t >> 9) & 7, ct = t >> 12;
        int k = kt * 32 + (l >> 4) * 8 + j;
        int col = ct * 16 + (l & 15);
        float v = W1[k * HC1 + col];
        __bf16 h = (__bf16)v;
        hi1[t] = h;
        lo1[t] = (__bf16)(v - (float)h);
    } else {
        int t = tid - F_IN * HC1;
        int j = t & 7, l = (t >> 3) & 63, kt = (t >> 9) & 3, ct = t >> 11;
        int k = kt * 32 + (l >> 4) * 8 + j;
        int col = ct * 16 + (l & 15);
        float v = W2[k * F_OUT + col];
        __bf16 h = (__bf16)v;
        hi2[t] = h;
        lo2[t] = (__bf16)(v - (float)h);
    }
}

// -------------------- fused gemm1 + bappend (bappend at grid front) -----------
// R29: exact R27 gemm1 structure (B prologue AFTER staging -- the R28 hoist
// regressed: +8 VGPR live across the barrier lengthened the schedule).

__global__ __launch_bounds__(256) void gemm1_bappend_kernel(
        const float* __restrict__ A,
        const __bf16* __restrict__ Whi, const __bf16* __restrict__ Wlo,
        const float* __restrict__ a_s, const float* __restrict__ a_d,
        __bf16* __restrict__ Cout, float* __restrict__ als, float* __restrict__ ald,
        const int* __restrict__ ei, int* __restrict__ bcur, int2* __restrict__ bstage) {
    __shared__ __bf16 ah[16][F_IN + 8];
    __shared__ __bf16 al[16][F_IN + 8];
    __shared__ int lcnt[NBKT];
    int tid = threadIdx.x;

    if (blockIdx.x < NAB) {
        const int TOT = E_EDGES + N_NODES;
        int bb = (int)blockIdx.x;
        int e0 = bb * APB;
        int e1 = e0 + APB < TOT ? e0 + APB : TOT;
        if (tid < NBKT) lcnt[tid] = 0;
        __syncthreads();
        for (int i = e0 + tid; i < e1; i += 256) {
            int d = (i < E_EDGES) ? ei[E_EDGES + i] : (i - E_EDGES);
            atomicAdd(&lcnt[d >> 8], 1);
        }
        __syncthreads();
        if (tid < NBKT) {
            int c = lcnt[tid];
            lcnt[tid] = c ? atomicAdd(&bcur[tid], c) : 0;
        }
        __syncthreads();
        for (int i = e0 + tid; i < e1; i += 256) {
            int s, d;
            if (i < E_EDGES) { s = ei[i]; d = ei[E_EDGES + i]; }
            else             { s = d = i - E_EDGES; }
            int b = d >> 8;
            int pos = atomicAdd(&lcnt[b], 1);
            bstage[(size_t)b * BMAX + pos] = make_int2(s, d);
        }
        return;
    }

    // gemm1 tile (KDIM=256, NC=128): 16 rows, 4 waves x CTW=2 col tiles
    constexpr int KT = 8, CTW = 2, F4PR = 64;
    int tb = (int)blockIdx.x - NAB;
    #pragma unroll
    for (int it = 0; it < 4; ++it) {
        int idx = it * 256 + tid;
        int row = idx / F4PR;
        int kk  = (idx - row * F4PR) * 4;
        int grow = tb * 16 + row;                 // GB1*16 == N_NODES: in range
        const float* src = A + (size_t)grow * F_IN + kk;
        float4 v = *(const float4*)src;
        bf16x4 h, lo;
        h[0] = (__bf16)v.x; h[1] = (__bf16)v.y; h[2] = (__bf16)v.z; h[3] = (__bf16)v.w;
        lo[0] = (__bf16)(v.x - (float)h[0]);
        lo[1] = (__bf16)(v.y - (float)h[1]);
        lo[2] = (__bf16)(v.z - (float)h[2]);
        lo[3] = (__bf16)(v.w - (float)h[3]);
        *(bf16x4*)&ah[row][kk] = h;
        *(bf16x4*)&al[row][kk] = lo;
    }
    __syncthreads();

    int w = tid >> 6, l = tid & 63;
    int c0 = w * CTW;                             // wave w covers head w
    int r0 = tb * 16;
    int rowL = l & 15;
    int koff = (l >> 4) * 8;

    bf16x8 bh[2][CTW], bl[2][CTW];
    #pragma unroll
    for (int c = 0; c < CTW; ++c) {
        size_t bidx = ((size_t)((c0 + c) * KT + 0) * 64 + l) * 8;
        bh[0][c] = *(const bf16x8*)(Whi + bidx);
        bl[0][c] = *(const bf16x8*)(Wlo + bidx);
    }

    f32x4 acc[CTW];
    #pragma unroll
    for (int c = 0; c < CTW; ++c) acc[c] = (f32x4){0.f, 0.f, 0.f, 0.f};

    #pragma unroll
    for (int kt = 0; kt < KT; ++kt) {
        const int cur = kt & 1, nxt = cur ^ 1;
        if (kt + 1 < KT) {
            #pragma unroll
            for (int c = 0; c < CTW; ++c) {
                size_t bidx = ((size_t)((c0 + c) * KT + (kt + 1)) * 64 + l) * 8;
                bh[nxt][c] = *(const bf16x8*)(Whi + bidx);
                bl[nxt][c] = *(const bf16x8*)(Wlo + bidx);
            }
        }
        bf16x8 ahi = *(const bf16x8*)&ah[rowL][kt * 32 + koff];
        bf16x8 alo = *(const bf16x8*)&al[rowL][kt * 32 + koff];
        #pragma unroll
        for (int c = 0; c < CTW; ++c) {
            acc[c] = __builtin_amdgcn_mfma_f32_16x16x32_bf16(ahi, bh[cur][c], acc[c], 0, 0, 0);
            acc[c] = __builtin_amdgcn_mfma_f32_16x16x32_bf16(ahi, bl[cur][c], acc[c], 0, 0, 0);
            acc[c] = __builtin_amdgcn_mfma_f32_16x16x32_bf16(alo, bh[cur][c], acc[c], 0, 0, 0);
        }
    }

    int crow0 = r0 + (l >> 4) * 4;
    int ccol = l & 15;

    #pragma unroll
    for (int c = 0; c < CTW; ++c) {
        #pragma unroll
        for (int r = 0; r < 4; ++r) {
            int row = crow0 + r;
            Cout[(size_t)row * HC1 + (c0 + c) * 16 + ccol] = (__bf16)acc[c][r];
        }
    }

    float as_c[CTW], ad_c[CTW];
    #pragma unroll
    for (int c = 0; c < CTW; ++c) {
        as_c[c] = a_s[(c0 + c) * 16 + ccol];
        ad_c[c] = a_d[(c0 + c) * 16 + ccol];
    }

    #pragma unroll
    for (int r = 0; r < 4; ++r) {
        int row = crow0 + r;
        float vs = acc[0][r] * as_c[0] + acc[1][r] * as_c[1];
        float vd = acc[0][r] * ad_c[0] + acc[1][r] * ad_c[1];
        #pragma unroll
        for (int d = 1; d < 16; d <<= 1) {
            vs += __shfl_xor(vs, d);
            vd += __shfl_xor(vd, d);
        }
        if (ccol == 0) { als[row * 4 + w] = vs; ald[row * 4 + w] = vd; }
    }
}

// -------------------- bsort + fused p1 (p1 stored as bf16) --------------------

__global__ __launch_bounds__(1024) void bsortp1_kernel(const int* __restrict__ bcur,
                                                       const int2* __restrict__ bstage,
                                                       const float* __restrict__ als1,
                                                       const float* __restrict__ ald1,
                                                       int* __restrict__ rowp,
                                                       int2* __restrict__ epair,
                                                       __bf16* __restrict__ p1) {
    __shared__ int cnt[256], cur[256], ws4[4];
    __shared__ int bbase_s;
    __shared__ int2 sorted[BMAX];
    int b = blockIdx.x, tid = threadIdx.x;
    int nb = bcur[b]; if (nb > BMAX) nb = BMAX;
    int d0 = b << 8;

    if (tid < 256) {
        int lane = tid & 63, w = tid >> 6;
        int v = (tid < NBKT) ? bcur[tid] : 0;
        int s = v;
        #pragma unroll
        for (int d = 1; d < 64; d <<= 1) {
            int t = __shfl_up(s, d);
            if (lane >= d) s += t;
        }
        if (lane == 63) ws4[w] = s;
        __syncthreads();
        if (tid == 0) {
            int r = 0;
            #pragma unroll
            for (int q = 0; q < 4; ++q) { int t = ws4[q]; ws4[q] = r; r += t; }
        }
        __syncthreads();
        if (tid == b) bbase_s = ws4[w] + s - v;
        if (b == 0 && tid == 0) rowp[N_NODES] = E_EDGES + N_NODES;
    } else {
        __syncthreads();
        __syncthreads();
    }
    if (tid < 256) cnt[tid] = 0;
    __syncthreads();
    int base = bbase_s;

    const int2* bs = bstage + (size_t)b * BMAX;
    for (int e = tid; e < nb; e += 1024)
        atomicAdd(&cnt[bs[e].y - d0], 1);
    __syncthreads();
    int v = 0, s = 0;
    if (tid < 256) {
        int lane = tid & 63, w = tid >> 6;
        v = cnt[tid];
        s = v;
        #pragma unroll
        for (int d = 1; d < 64; d <<= 1) {
            int t = __shfl_up(s, d);
            if (lane >= d) s += t;
        }
        if (lane == 63) ws4[w] = s;
    }
    __syncthreads();
    if (tid == 0) {
        int r = 0;
        #pragma unroll
        for (int q = 0; q < 4; ++q) { int t = ws4[q]; ws4[q] = r; r += t; }
    }
    __syncthreads();
    if (tid < 256) {
        int excl = ws4[tid >> 6] + s - v;
        cur[tid] = excl;
        int d = d0 + tid;
        if (d < N_NODES) rowp[d] = base + excl;
    }
    __syncthreads();
    for (int e = tid; e < nb; e += 1024) {
        int2 ed = bs[e];
        int p = atomicAdd(&cur[ed.y - d0], 1);
        sorted[p] = ed;
    }
    __syncthreads();
    for (int e = tid; e < nb; e += 1024) {
        int2 ed = sorted[e];
        epair[base + e] = ed;
        float4 as = *(const float4*)&als1[ed.x * 4];
        float4 ad = *(const float4*)&ald1[ed.y * 4];
        bf16x4 p;
        p[0] = (__bf16)__expf(lrelu(as.x + ad.x));
        p[1] = (__bf16)__expf(lrelu(as.y + ad.y));
        p[2] = (__bf16)__expf(lrelu(as.z + ad.z));
        p[3] = (__bf16)__expf(lrelu(as.w + ad.w));
        *(bf16x4*)&p1[(size_t)(base + e) * 4] = p;
    }
}

// -------------------- fused aggr1 + gemm2 -------------------------------------
// 4 waves x 4 sequential dsts (variance smoothing) + 2x edge unroll with
// (s,p) prefetch; p1 read as bf16 (half the stream bytes).

__global__ __launch_bounds__(256) void aggr1g_kernel(
        const int* __restrict__ rowp, const int2* __restrict__ epair,
        const __bf16* __restrict__ p1, const __bf16* __restrict__ h1b,
        const float* __restrict__ b1,
        const __bf16* __restrict__ whi2, const __bf16* __restrict__ wlo2,
        const float* __restrict__ a_src2, const float* __restrict__ a_dst2,
        float* __restrict__ g, float* __restrict__ als2, float* __restrict__ ald2) {
    __shared__ __bf16 h2h[16][HC1 + 8];
    __shared__ __bf16 h2l[16][HC1 + 8];
    __shared__ float alsp[4][16], aldp[4][16];
    int tid = threadIdx.x;
    int w = tid >> 6, l = tid & 63;
    int grp = l >> 4, li = l & 15;         // 4 groups x 16 lanes, 8 cols/lane
    int hh = li >> 2;

    #pragma unroll
    for (int q = 0; q < 4; ++q) {
        int row = w * 4 + q;
        int wid = blockIdx.x * 16 + row;
        int beg = rowp[wid], end = rowp[wid + 1];

        float acc[8] = {0,0,0,0,0,0,0,0};
        float S = 0.f;

        int ja = beg + grp, jb = beg + 4 + grp;
        int sa = 0, sb = 0; float pa = 0.f, pb = 0.f;
        if (ja < end) { sa = epair[ja].x; pa = (float)p1[(size_t)ja * 4 + hh]; }
        if (jb < end) { sb = epair[jb].x; pb = (float)p1[(size_t)jb * 4 + hh]; }
        for (int j0 = beg; j0 < end; j0 += 8) {
            int jan = j0 + 8 + grp, jbn = j0 + 12 + grp;
            int san = 0, sbn = 0; float pan = 0.f, pbn = 0.f;
            if (jan < end) { san = epair[jan].x; pan = (float)p1[(size_t)jan * 4 + hh]; }
            if (jbn < end) { sbn = epair[jbn].x; pbn = (float)p1[(size_t)jbn * 4 + hh]; }
            uint4 va = *(const uint4*)(h1b + (size_t)sa * HC1 + li * 8);
            uint4 vb = *(const uint4*)(h1b + (size_t)sb * HC1 + li * 8);
            acc[0] += pa * bflo(va.x) + pb * bflo(vb.x);
            acc[1] += pa * bfhi(va.x) + pb * bfhi(vb.x);
            acc[2] += pa * bflo(va.y) + pb * bflo(vb.y);
            acc[3] += pa * bfhi(va.y) + pb * bfhi(vb.y);
            acc[4] += pa * bflo(va.z) + pb * bflo(vb.z);
            acc[5] += pa * bfhi(va.z) + pb * bfhi(vb.z);
            acc[6] += pa * bflo(va.w) + pb * bflo(vb.w);
            acc[7] += pa * bfhi(va.w) + pb * bfhi(vb.w);
            S += pa + pb;
            sa = san; pa = pan; sb = sbn; pb = pbn;
        }
        #pragma unroll
        for (int d = 16; d < 64; d <<= 1) {
            #pragma unroll
            for (int c = 0; c < 8; ++c) acc[c] += __shfl_xor(acc[c], d);
            S += __shfl_xor(S, d);
        }
        if (grp == 0) {
            float inv = 1.f / S;
            const float* bp = b1 + li * 8;
            bf16x8 hv, lv;
            #pragma unroll
            for (int c = 0; c < 8; ++c) {
                float o = lrelu(acc[c] * inv + bp[c]);
                __bf16 h = (__bf16)o;
                hv[c] = h;
                lv[c] = (__bf16)(o - (float)h);
            }
            *(bf16x8*)&h2h[row][li * 8] = hv;
            *(bf16x8*)&h2l[row][li * 8] = lv;
        }
    }
    __syncthreads();

    // ---- gemm2 for this block's 16 h2 rows: 4 waves, one col-tile each ----
    {
        constexpr int KT = 4;
        int c0 = w;
        bf16x8 bh[KT], bl[KT];
        #pragma unroll
        for (int kt = 0; kt < KT; ++kt) {
            size_t bidx = ((size_t)(c0 * KT + kt) * 64 + l) * 8;
            bh[kt] = *(const bf16x8*)(whi2 + bidx);
            bl[kt] = *(const bf16x8*)(wlo2 + bidx);
        }
        int ar = l & 15, koff = (l >> 4) * 8;
        f32x4 acc2 = (f32x4){0.f, 0.f, 0.f, 0.f};
        #pragma unroll
        for (int kt = 0; kt < KT; ++kt) {
            bf16x8 ahi = *(const bf16x8*)&h2h[ar][kt * 32 + koff];
            bf16x8 alo = *(const bf16x8*)&h2l[ar][kt * 32 + koff];
            acc2 = __builtin_amdgcn_mfma_f32_16x16x32_bf16(ahi, bh[kt], acc2, 0, 0, 0);
            acc2 = __builtin_amdgcn_mfma_f32_16x16x32_bf16(ahi, bl[kt], acc2, 0, 0, 0);
            acc2 = __builtin_amdgcn_mfma_f32_16x16x32_bf16(alo, bh[kt], acc2, 0, 0, 0);
        }
        int crow0 = (l >> 4) * 4;
        int ccol = l & 15;
        float as_c = a_src2[c0 * 16 + ccol];
        float ad_c = a_dst2[c0 * 16 + ccol];
        #pragma unroll
        for (int r = 0; r < 4; ++r) {
            int row = blockIdx.x * 16 + crow0 + r;
            g[(size_t)row * F_OUT + c0 * 16 + ccol] = acc2[r];
            float vs = acc2[r] * as_c;
            float vd = acc2[r] * ad_c;
            #pragma unroll
            for (int d = 1; d < 16; d <<= 1) {
                vs += __shfl_xor(vs, d);
                vd += __shfl_xor(vd, d);
            }
            if (ccol == 0) { alsp[c0][crow0 + r] = vs; aldp[c0][crow0 + r] = vd; }
        }
    }
    __syncthreads();
    if (tid < 16) {
        als2[blockIdx.x * 16 + tid] = alsp[0][tid] + alsp[1][tid] + alsp[2][tid] + alsp[3][tid];
        ald2[blockIdx.x * 16 + tid] = aldp[0][tid] + aldp[1][tid] + aldp[2][tid] + aldp[3][tid];
    }
}

// -------------------- aggr2 (inline p2, 8x8 groups + prefetch) ----------------

__global__ __launch_bounds__(256) void aggr2_kernel(const int* __restrict__ row_ptr,
                                                    const int2* __restrict__ epair,
                                                    const float* __restrict__ als2,
                                                    const float* __restrict__ ald2,
                                                    const float* __restrict__ g,
                                                    const float* __restrict__ b2,
                                                    float* __restrict__ out) {
    int wid = blockIdx.x * 4 + (threadIdx.x >> 6);
    int lane = threadIdx.x & 63;
    int grp = lane >> 3, li = lane & 7;    // 8 groups x 8 lanes, 8 cols/lane
    int beg = row_ptr[wid], end = row_ptr[wid + 1];
    float ad = ald2[wid];
    float a[8];
    #pragma unroll
    for (int c = 0; c < 8; ++c) a[c] = 0.f;
    float S = 0.f;

    int j = beg + grp;
    int s_c = 0; float p_c = 0.f;
    if (j < end) { s_c = epair[j].x; p_c = __expf(lrelu(als2[s_c] + ad)); }
    for (int j0 = beg; j0 < end; j0 += 8) {
        int jn = j0 + 8 + grp;
        int s_n = 0; float p_n = 0.f;
        if (jn < end) { s_n = epair[jn].x; p_n = __expf(lrelu(als2[s_n] + ad)); }
        const float* grow = g + (size_t)s_c * F_OUT + li * 8;
        float4 g0 = *(const float4*)grow;
        float4 g1 = *(const float4*)(grow + 4);
        a[0] += p_c * g0.x; a[1] += p_c * g0.y; a[2] += p_c * g0.z; a[3] += p_c * g0.w;
        a[4] += p_c * g1.x; a[5] += p_c * g1.y; a[6] += p_c * g1.z; a[7] += p_c * g1.w;
        S += p_c;
        s_c = s_n; p_c = p_n;
    }
    #pragma unroll
    for (int d = 8; d < 64; d <<= 1) {
        #pragma unroll
        for (int c = 0; c < 8; ++c) a[c] += __shfl_xor(a[c], d);
        S += __shfl_xor(S, d);
    }
    if (grp == 0) {
        float inv = 1.f / S;
        const float* bp = b2 + li * 8;
        float4 o0, o1;
        o0.x = a[0] * inv + bp[0];
        o0.y = a[1] * inv + bp[1];
        o0.z = a[2] * inv + bp[2];
        o0.w = a[3] * inv + bp[3];
        o1.x = a[4] * inv + bp[4];
        o1.y = a[5] * inv + bp[5];
        o1.z = a[6] * inv + bp[6];
        o1.w = a[7] * inv + bp[7];
        float* orow = out + (size_t)wid * F_OUT + li * 8;
        *(float4*)orow = o0;
        *(float4*)(orow + 4) = o1;
    }
}

// -------------------- launch --------------------------------------------------

extern "C" void kernel_launch(void* const* d_in, const int* in_sizes, int n_in,
                              void* d_out, int out_size, void* d_ws, size_t ws_size,
                              hipStream_t stream) {
    const float* x      = (const float*)d_in[0];
    const int*   ei     = (const int*)  d_in[1];
    const float* W1     = (const float*)d_in[2];
    const float* a_src1 = (const float*)d_in[3];
    const float* a_dst1 = (const float*)d_in[4];
    const float* b1     = (const float*)d_in[5];
    const float* W2     = (const float*)d_in[6];
    const float* a_src2 = (const float*)d_in[7];
    const float* a_dst2 = (const float*)d_in[8];
    const float* b2     = (const float*)d_in[9];
    float* out = (float*)d_out;
    char* ws = (char*)d_ws;

    // workspace layout (bytes)
    __bf16* h1b    = (__bf16*)(ws + 0);         // N*128*2 = 12,800,000
    __bf16* p1     = (__bf16*)(ws + 12800000);  // (E+N)*4*2 = 5,200,000
    float* g       = (float*)(ws + 38400000);   // N*64*4 = 12,800,000
    float* als1    = (float*)(ws + 51200000);   // 800,000
    float* ald1    = (float*)(ws + 52000000);   // 800,000
    float* als2    = (float*)(ws + 52800000);   // 200,000
    float* ald2    = (float*)(ws + 53000000);   // 200,000
    int*   rowp    = (int*)  (ws + 53200000);   // 200,004 (pad to 53,400,064)
    int*   bcur    = (int*)  (ws + 53400064);   // 784 (pad to 53,402,112)
    int2*  bstage  = (int2*) (ws + 53402112);   // NBKT*BMAX*8 = 9,633,792 -> 63,035,904
    int2*  epair   = (int2*) (ws + 63035904);   // (E+N)*8 = 5,200,000 -> 68,235,904
    __bf16* whi1   = (__bf16*)(ws + 68235904);  // 65,536
    __bf16* wlo1   = (__bf16*)(ws + 68301440);  // 65,536
    __bf16* whi2   = (__bf16*)(ws + 68366976);  // 16,384
    __bf16* wlo2   = (__bf16*)(ws + 68383360);  // 16,384 (end 68,399,744)

    init_kernel<<<1 + (NPACK + 255) / 256, 256, 0, stream>>>(
        W1, W2, whi1, wlo1, whi2, wlo2, bcur);

    gemm1_bappend_kernel<<<NAB + GB1, 256, 0, stream>>>(
        x, whi1, wlo1, a_src1, a_dst1, h1b, als1, ald1, ei, bcur, bstage);

    bsortp1_kernel<<<NBKT, 1024, 0, stream>>>(bcur, bstage, als1, ald1, rowp, epair, p1);

    aggr1g_kernel<<<N_NODES / 16, 256, 0, stream>>>(
        rowp, epair, p1, h1b, b1, whi2, wlo2, a_src2, a_dst2, g, als2, ald2);

    aggr2_kernel<<<N_NODES / 4, 256, 0, stream>>>(rowp, epair, als2, ald2, g, b2, out);
}

// Round 30
// 117.092 us; speedup vs baseline: 1.0292x; 1.0292x over previous
//
#include <hip/hip_runtime.h>
#include <hip/hip_bf16.h>

#define N_NODES 50000
#define E_EDGES 600000
#define F_IN    256
#define HC1     128   // 4 heads * 32
#define F_OUT   64
#define NBKT    196   // ceil(N_NODES/256) coarse dst-buckets
#define BMAX    6144  // per-bucket capacity (mean 3316, sigma ~58)
#define APB     8192  // edges per bappend chunk
#define NAB     80    // ceil((E+N)/APB)
#define GB1     3125  // gemm1 tile blocks = N/16 (exact)
#define NPACK   (F_IN * HC1 + HC1 * F_OUT)   // 40960

typedef __bf16 bf16x8 __attribute__((ext_vector_type(8)));
typedef __bf16 bf16x4 __attribute__((ext_vector_type(4)));
typedef float  f32x4  __attribute__((ext_vector_type(4)));

__device__ __forceinline__ float lrelu(float x) { return x > 0.f ? x : 0.2f * x; }
__device__ __forceinline__ float bfhi(unsigned v) { return __uint_as_float(v & 0xffff0000u); }
__device__ __forceinline__ float bflo(unsigned v) { return __uint_as_float(v << 16); }

// -------------------- init: zero bucket cursors + pack W (fused) --------------

__global__ __launch_bounds__(256) void init_kernel(const float* __restrict__ W1,
                                                   const float* __restrict__ W2,
                                                   __bf16* __restrict__ hi1, __bf16* __restrict__ lo1,
                                                   __bf16* __restrict__ hi2, __bf16* __restrict__ lo2,
                                                   int* __restrict__ bcur) {
    if (blockIdx.x == 0) {
        if (threadIdx.x < NBKT) bcur[threadIdx.x] = 0;
        return;
    }
    int tid = (blockIdx.x - 1) * 256 + threadIdx.x;
    if (tid >= NPACK) return;
    if (tid < F_IN * HC1) {
        int t = tid;
        int j = t & 7, l = (t >> 3) & 63, kt = (t >> 9) & 7, ct = t >> 12;
        int k = kt * 32 + (l >> 4) * 8 + j;
        int col = ct * 16 + (l & 15);
        float v = W1[k * HC1 + col];
        __bf16 h = (__bf16)v;
        hi1[t] = h;
        lo1[t] = (__bf16)(v - (float)h);
    } else {
        int t = tid - F_IN * HC1;
        int j = t & 7, l = (t >> 3) & 63, kt = (t >> 9) & 3, ct = t >> 11;
        int k = kt * 32 + (l >> 4) * 8 + j;
        int col = ct * 16 + (l & 15);
        float v = W2[k * F_OUT + col];
        __bf16 h = (__bf16)v;
        hi2[t] = h;
        lo2[t] = (__bf16)(v - (float)h);
    }
}

// -------------------- fused gemm1 + bappend (bappend at grid front) -----------
// Exact R27 structure (116.6us): 16-row gemm1 tile, 4 waves (wave = one head,
// CTW=2), B prologue after staging, p1 kept fp32 downstream (R28/R29 matched
// pair showed both micro-variants regress).

__global__ __launch_bounds__(256) void gemm1_bappend_kernel(
        const float* __restrict__ A,
        const __bf16* __restrict__ Whi, const __bf16* __restrict__ Wlo,
        const float* __restrict__ a_s, const float* __restrict__ a_d,
        __bf16* __restrict__ Cout, float* __restrict__ als, float* __restrict__ ald,
        const int* __restrict__ ei, int* __restrict__ bcur, int2* __restrict__ bstage) {
    __shared__ __bf16 ah[16][F_IN + 8];
    __shared__ __bf16 al[16][F_IN + 8];
    __shared__ int lcnt[NBKT];
    int tid = threadIdx.x;

    if (blockIdx.x < NAB) {
        const int TOT = E_EDGES + N_NODES;
        int bb = (int)blockIdx.x;
        int e0 = bb * APB;
        int e1 = e0 + APB < TOT ? e0 + APB : TOT;
        if (tid < NBKT) lcnt[tid] = 0;
        __syncthreads();
        for (int i = e0 + tid; i < e1; i += 256) {
            int d = (i < E_EDGES) ? ei[E_EDGES + i] : (i - E_EDGES);
            atomicAdd(&lcnt[d >> 8], 1);
        }
        __syncthreads();
        if (tid < NBKT) {
            int c = lcnt[tid];
            lcnt[tid] = c ? atomicAdd(&bcur[tid], c) : 0;
        }
        __syncthreads();
        for (int i = e0 + tid; i < e1; i += 256) {
            int s, d;
            if (i < E_EDGES) { s = ei[i]; d = ei[E_EDGES + i]; }
            else             { s = d = i - E_EDGES; }
            int b = d >> 8;
            int pos = atomicAdd(&lcnt[b], 1);
            bstage[(size_t)b * BMAX + pos] = make_int2(s, d);
        }
        return;
    }

    // gemm1 tile (KDIM=256, NC=128): 16 rows, 4 waves x CTW=2 col tiles
    constexpr int KT = 8, CTW = 2, F4PR = 64;
    int tb = (int)blockIdx.x - NAB;
    #pragma unroll
    for (int it = 0; it < 4; ++it) {
        int idx = it * 256 + tid;
        int row = idx / F4PR;
        int kk  = (idx - row * F4PR) * 4;
        int grow = tb * 16 + row;                 // GB1*16 == N_NODES: in range
        const float* src = A + (size_t)grow * F_IN + kk;
        float4 v = *(const float4*)src;
        bf16x4 h, lo;
        h[0] = (__bf16)v.x; h[1] = (__bf16)v.y; h[2] = (__bf16)v.z; h[3] = (__bf16)v.w;
        lo[0] = (__bf16)(v.x - (float)h[0]);
        lo[1] = (__bf16)(v.y - (float)h[1]);
        lo[2] = (__bf16)(v.z - (float)h[2]);
        lo[3] = (__bf16)(v.w - (float)h[3]);
        *(bf16x4*)&ah[row][kk] = h;
        *(bf16x4*)&al[row][kk] = lo;
    }
    __syncthreads();

    int w = tid >> 6, l = tid & 63;
    int c0 = w * CTW;                             // wave w covers head w
    int r0 = tb * 16;
    int rowL = l & 15;
    int koff = (l >> 4) * 8;

    bf16x8 bh[2][CTW], bl[2][CTW];
    #pragma unroll
    for (int c = 0; c < CTW; ++c) {
        size_t bidx = ((size_t)((c0 + c) * KT + 0) * 64 + l) * 8;
        bh[0][c] = *(const bf16x8*)(Whi + bidx);
        bl[0][c] = *(const bf16x8*)(Wlo + bidx);
    }

    f32x4 acc[CTW];
    #pragma unroll
    for (int c = 0; c < CTW; ++c) acc[c] = (f32x4){0.f, 0.f, 0.f, 0.f};

    #pragma unroll
    for (int kt = 0; kt < KT; ++kt) {
        const int cur = kt & 1, nxt = cur ^ 1;
        if (kt + 1 < KT) {
            #pragma unroll
            for (int c = 0; c < CTW; ++c) {
                size_t bidx = ((size_t)((c0 + c) * KT + (kt + 1)) * 64 + l) * 8;
                bh[nxt][c] = *(const bf16x8*)(Whi + bidx);
                bl[nxt][c] = *(const bf16x8*)(Wlo + bidx);
            }
        }
        bf16x8 ahi = *(const bf16x8*)&ah[rowL][kt * 32 + koff];
        bf16x8 alo = *(const bf16x8*)&al[rowL][kt * 32 + koff];
        #pragma unroll
        for (int c = 0; c < CTW; ++c) {
            acc[c] = __builtin_amdgcn_mfma_f32_16x16x32_bf16(ahi, bh[cur][c], acc[c], 0, 0, 0);
            acc[c] = __builtin_amdgcn_mfma_f32_16x16x32_bf16(ahi, bl[cur][c], acc[c], 0, 0, 0);
            acc[c] = __builtin_amdgcn_mfma_f32_16x16x32_bf16(alo, bh[cur][c], acc[c], 0, 0, 0);
        }
    }

    int crow0 = r0 + (l >> 4) * 4;
    int ccol = l & 15;

    #pragma unroll
    for (int c = 0; c < CTW; ++c) {
        #pragma unroll
        for (int r = 0; r < 4; ++r) {
            int row = crow0 + r;
            Cout[(size_t)row * HC1 + (c0 + c) * 16 + ccol] = (__bf16)acc[c][r];
        }
    }

    float as_c[CTW], ad_c[CTW];
    #pragma unroll
    for (int c = 0; c < CTW; ++c) {
        as_c[c] = a_s[(c0 + c) * 16 + ccol];
        ad_c[c] = a_d[(c0 + c) * 16 + ccol];
    }

    #pragma unroll
    for (int r = 0; r < 4; ++r) {
        int row = crow0 + r;
        float vs = acc[0][r] * as_c[0] + acc[1][r] * as_c[1];
        float vd = acc[0][r] * ad_c[0] + acc[1][r] * ad_c[1];
        #pragma unroll
        for (int d = 1; d < 16; d <<= 1) {
            vs += __shfl_xor(vs, d);
            vd += __shfl_xor(vd, d);
        }
        if (ccol == 0) { als[row * 4 + w] = vs; ald[row * 4 + w] = vd; }
    }
}

// -------------------- bsort + fused p1 (p1 fp32) -------------------------------

__global__ __launch_bounds__(1024) void bsortp1_kernel(const int* __restrict__ bcur,
                                                       const int2* __restrict__ bstage,
                                                       const float* __restrict__ als1,
                                                       const float* __restrict__ ald1,
                                                       int* __restrict__ rowp,
                                                       int2* __restrict__ epair,
                                                       float* __restrict__ p1) {
    __shared__ int cnt[256], cur[256], ws4[4];
    __shared__ int bbase_s;
    __shared__ int2 sorted[BMAX];
    int b = blockIdx.x, tid = threadIdx.x;
    int nb = bcur[b]; if (nb > BMAX) nb = BMAX;
    int d0 = b << 8;

    if (tid < 256) {
        int lane = tid & 63, w = tid >> 6;
        int v = (tid < NBKT) ? bcur[tid] : 0;
        int s = v;
        #pragma unroll
        for (int d = 1; d < 64; d <<= 1) {
            int t = __shfl_up(s, d);
            if (lane >= d) s += t;
        }
        if (lane == 63) ws4[w] = s;
        __syncthreads();
        if (tid == 0) {
            int r = 0;
            #pragma unroll
            for (int q = 0; q < 4; ++q) { int t = ws4[q]; ws4[q] = r; r += t; }
        }
        __syncthreads();
        if (tid == b) bbase_s = ws4[w] + s - v;
        if (b == 0 && tid == 0) rowp[N_NODES] = E_EDGES + N_NODES;
    } else {
        __syncthreads();
        __syncthreads();
    }
    if (tid < 256) cnt[tid] = 0;
    __syncthreads();
    int base = bbase_s;

    const int2* bs = bstage + (size_t)b * BMAX;
    for (int e = tid; e < nb; e += 1024)
        atomicAdd(&cnt[bs[e].y - d0], 1);
    __syncthreads();
    int v = 0, s = 0;
    if (tid < 256) {
        int lane = tid & 63, w = tid >> 6;
        v = cnt[tid];
        s = v;
        #pragma unroll
        for (int d = 1; d < 64; d <<= 1) {
            int t = __shfl_up(s, d);
            if (lane >= d) s += t;
        }
        if (lane == 63) ws4[w] = s;
    }
    __syncthreads();
    if (tid == 0) {
        int r = 0;
        #pragma unroll
        for (int q = 0; q < 4; ++q) { int t = ws4[q]; ws4[q] = r; r += t; }
    }
    __syncthreads();
    if (tid < 256) {
        int excl = ws4[tid >> 6] + s - v;
        cur[tid] = excl;
        int d = d0 + tid;
        if (d < N_NODES) rowp[d] = base + excl;
    }
    __syncthreads();
    for (int e = tid; e < nb; e += 1024) {
        int2 ed = bs[e];
        int p = atomicAdd(&cur[ed.y - d0], 1);
        sorted[p] = ed;
    }
    __syncthreads();
    for (int e = tid; e < nb; e += 1024) {
        int2 ed = sorted[e];
        epair[base + e] = ed;
        float4 as = *(const float4*)&als1[ed.x * 4];
        float4 ad = *(const float4*)&ald1[ed.y * 4];
        float4 p;
        p.x = __expf(lrelu(as.x + ad.x));
        p.y = __expf(lrelu(as.y + ad.y));
        p.z = __expf(lrelu(as.z + ad.z));
        p.w = __expf(lrelu(as.w + ad.w));
        *(float4*)&p1[(size_t)(base + e) * 4] = p;
    }
}

// -------------------- fused aggr1 + gemm2 -------------------------------------
// 4 waves x 4 sequential dsts (variance smoothing) + 2x edge unroll with
// (s,p) prefetch; p1 fp32.

__global__ __launch_bounds__(256) void aggr1g_kernel(
        const int* __restrict__ rowp, const int2* __restrict__ epair,
        const float* __restrict__ p1, const __bf16* __restrict__ h1b,
        const float* __restrict__ b1,
        const __bf16* __restrict__ whi2, const __bf16* __restrict__ wlo2,
        const float* __restrict__ a_src2, const float* __restrict__ a_dst2,
        float* __restrict__ g, float* __restrict__ als2, float* __restrict__ ald2) {
    __shared__ __bf16 h2h[16][HC1 + 8];
    __shared__ __bf16 h2l[16][HC1 + 8];
    __shared__ float alsp[4][16], aldp[4][16];
    int tid = threadIdx.x;
    int w = tid >> 6, l = tid & 63;
    int grp = l >> 4, li = l & 15;         // 4 groups x 16 lanes, 8 cols/lane
    int hh = li >> 2;

    #pragma unroll
    for (int q = 0; q < 4; ++q) {
        int row = w * 4 + q;
        int wid = blockIdx.x * 16 + row;
        int beg = rowp[wid], end = rowp[wid + 1];

        float acc[8] = {0,0,0,0,0,0,0,0};
        float S = 0.f;

        int ja = beg + grp, jb = beg + 4 + grp;
        int sa = 0, sb = 0; float pa = 0.f, pb = 0.f;
        if (ja < end) { sa = epair[ja].x; pa = p1[(size_t)ja * 4 + hh]; }
        if (jb < end) { sb = epair[jb].x; pb = p1[(size_t)jb * 4 + hh]; }
        for (int j0 = beg; j0 < end; j0 += 8) {
            int jan = j0 + 8 + grp, jbn = j0 + 12 + grp;
            int san = 0, sbn = 0; float pan = 0.f, pbn = 0.f;
            if (jan < end) { san = epair[jan].x; pan = p1[(size_t)jan * 4 + hh]; }
            if (jbn < end) { sbn = epair[jbn].x; pbn = p1[(size_t)jbn * 4 + hh]; }
            uint4 va = *(const uint4*)(h1b + (size_t)sa * HC1 + li * 8);
            uint4 vb = *(const uint4*)(h1b + (size_t)sb * HC1 + li * 8);
            acc[0] += pa * bflo(va.x) + pb * bflo(vb.x);
            acc[1] += pa * bfhi(va.x) + pb * bfhi(vb.x);
            acc[2] += pa * bflo(va.y) + pb * bflo(vb.y);
            acc[3] += pa * bfhi(va.y) + pb * bfhi(vb.y);
            acc[4] += pa * bflo(va.z) + pb * bflo(vb.z);
            acc[5] += pa * bfhi(va.z) + pb * bfhi(vb.z);
            acc[6] += pa * bflo(va.w) + pb * bflo(vb.w);
            acc[7] += pa * bfhi(va.w) + pb * bfhi(vb.w);
            S += pa + pb;
            sa = san; pa = pan; sb = sbn; pb = pbn;
        }
        #pragma unroll
        for (int d = 16; d < 64; d <<= 1) {
            #pragma unroll
            for (int c = 0; c < 8; ++c) acc[c] += __shfl_xor(acc[c], d);
            S += __shfl_xor(S, d);
        }
        if (grp == 0) {
            float inv = 1.f / S;
            const float* bp = b1 + li * 8;
            bf16x8 hv, lv;
            #pragma unroll
            for (int c = 0; c < 8; ++c) {
                float o = lrelu(acc[c] * inv + bp[c]);
                __bf16 h = (__bf16)o;
                hv[c] = h;
                lv[c] = (__bf16)(o - (float)h);
            }
            *(bf16x8*)&h2h[row][li * 8] = hv;
            *(bf16x8*)&h2l[row][li * 8] = lv;
        }
    }
    __syncthreads();

    // ---- gemm2 for this block's 16 h2 rows: 4 waves, one col-tile each ----
    {
        constexpr int KT = 4;
        int c0 = w;
        bf16x8 bh[KT], bl[KT];
        #pragma unroll
        for (int kt = 0; kt < KT; ++kt) {
            size_t bidx = ((size_t)(c0 * KT + kt) * 64 + l) * 8;
            bh[kt] = *(const bf16x8*)(whi2 + bidx);
            bl[kt] = *(const bf16x8*)(wlo2 + bidx);
        }
        int ar = l & 15, koff = (l >> 4) * 8;
        f32x4 acc2 = (f32x4){0.f, 0.f, 0.f, 0.f};
        #pragma unroll
        for (int kt = 0; kt < KT; ++kt) {
            bf16x8 ahi = *(const bf16x8*)&h2h[ar][kt * 32 + koff];
            bf16x8 alo = *(const bf16x8*)&h2l[ar][kt * 32 + koff];
            acc2 = __builtin_amdgcn_mfma_f32_16x16x32_bf16(ahi, bh[kt], acc2, 0, 0, 0);
            acc2 = __builtin_amdgcn_mfma_f32_16x16x32_bf16(ahi, bl[kt], acc2, 0, 0, 0);
            acc2 = __builtin_amdgcn_mfma_f32_16x16x32_bf16(alo, bh[kt], acc2, 0, 0, 0);
        }
        int crow0 = (l >> 4) * 4;
        int ccol = l & 15;
        float as_c = a_src2[c0 * 16 + ccol];
        float ad_c = a_dst2[c0 * 16 + ccol];
        #pragma unroll
        for (int r = 0; r < 4; ++r) {
            int row = blockIdx.x * 16 + crow0 + r;
            g[(size_t)row * F_OUT + c0 * 16 + ccol] = acc2[r];
            float vs = acc2[r] * as_c;
            float vd = acc2[r] * ad_c;
            #pragma unroll
            for (int d = 1; d < 16; d <<= 1) {
                vs += __shfl_xor(vs, d);
                vd += __shfl_xor(vd, d);
            }
            if (ccol == 0) { alsp[c0][crow0 + r] = vs; aldp[c0][crow0 + r] = vd; }
        }
    }
    __syncthreads();
    if (tid < 16) {
        als2[blockIdx.x * 16 + tid] = alsp[0][tid] + alsp[1][tid] + alsp[2][tid] + alsp[3][tid];
        ald2[blockIdx.x * 16 + tid] = aldp[0][tid] + aldp[1][tid] + aldp[2][tid] + aldp[3][tid];
    }
}

// -------------------- aggr2 (inline p2, 8x8 groups + prefetch) ----------------

__global__ __launch_bounds__(256) void aggr2_kernel(const int* __restrict__ row_ptr,
                                                    const int2* __restrict__ epair,
                                                    const float* __restrict__ als2,
                                                    const float* __restrict__ ald2,
                                                    const float* __restrict__ g,
                                                    const float* __restrict__ b2,
                                                    float* __restrict__ out) {
    int wid = blockIdx.x * 4 + (threadIdx.x >> 6);
    int lane = threadIdx.x & 63;
    int grp = lane >> 3, li = lane & 7;    // 8 groups x 8 lanes, 8 cols/lane
    int beg = row_ptr[wid], end = row_ptr[wid + 1];
    float ad = ald2[wid];
    float a[8];
    #pragma unroll
    for (int c = 0; c < 8; ++c) a[c] = 0.f;
    float S = 0.f;

    int j = beg + grp;
    int s_c = 0; float p_c = 0.f;
    if (j < end) { s_c = epair[j].x; p_c = __expf(lrelu(als2[s_c] + ad)); }
    for (int j0 = beg; j0 < end; j0 += 8) {
        int jn = j0 + 8 + grp;
        int s_n = 0; float p_n = 0.f;
        if (jn < end) { s_n = epair[jn].x; p_n = __expf(lrelu(als2[s_n] + ad)); }
        const float* grow = g + (size_t)s_c * F_OUT + li * 8;
        float4 g0 = *(const float4*)grow;
        float4 g1 = *(const float4*)(grow + 4);
        a[0] += p_c * g0.x; a[1] += p_c * g0.y; a[2] += p_c * g0.z; a[3] += p_c * g0.w;
        a[4] += p_c * g1.x; a[5] += p_c * g1.y; a[6] += p_c * g1.z; a[7] += p_c * g1.w;
        S += p_c;
        s_c = s_n; p_c = p_n;
    }
    #pragma unroll
    for (int d = 8; d < 64; d <<= 1) {
        #pragma unroll
        for (int c = 0; c < 8; ++c) a[c] += __shfl_xor(a[c], d);
        S += __shfl_xor(S, d);
    }
    if (grp == 0) {
        float inv = 1.f / S;
        const float* bp = b2 + li * 8;
        float4 o0, o1;
        o0.x = a[0] * inv + bp[0];
        o0.y = a[1] * inv + bp[1];
        o0.z = a[2] * inv + bp[2];
        o0.w = a[3] * inv + bp[3];
        o1.x = a[4] * inv + bp[4];
        o1.y = a[5] * inv + bp[5];
        o1.z = a[6] * inv + bp[6];
        o1.w = a[7] * inv + bp[7];
        float* orow = out + (size_t)wid * F_OUT + li * 8;
        *(float4*)orow = o0;
        *(float4*)(orow + 4) = o1;
    }
}

// -------------------- launch --------------------------------------------------

extern "C" void kernel_launch(void* const* d_in, const int* in_sizes, int n_in,
                              void* d_out, int out_size, void* d_ws, size_t ws_size,
                              hipStream_t stream) {
    const float* x      = (const float*)d_in[0];
    const int*   ei     = (const int*)  d_in[1];
    const float* W1     = (const float*)d_in[2];
    const float* a_src1 = (const float*)d_in[3];
    const float* a_dst1 = (const float*)d_in[4];
    const float* b1     = (const float*)d_in[5];
    const float* W2     = (const float*)d_in[6];
    const float* a_src2 = (const float*)d_in[7];
    const float* a_dst2 = (const float*)d_in[8];
    const float* b2     = (const float*)d_in[9];
    float* out = (float*)d_out;
    char* ws = (char*)d_ws;

    // workspace layout (bytes)
    __bf16* h1b    = (__bf16*)(ws + 0);         // N*128*2 = 12,800,000
    float* p1      = (float*)(ws + 12800000);   // (E+N)*4*4 = 10,400,000
    float* g       = (float*)(ws + 38400000);   // N*64*4 = 12,800,000
    float* als1    = (float*)(ws + 51200000);   // 800,000
    float* ald1    = (float*)(ws + 52000000);   // 800,000
    float* als2    = (float*)(ws + 52800000);   // 200,000
    float* ald2    = (float*)(ws + 53000000);   // 200,000
    int*   rowp    = (int*)  (ws + 53200000);   // 200,004 (pad to 53,400,064)
    int*   bcur    = (int*)  (ws + 53400064);   // 784 (pad to 53,402,112)
    int2*  bstage  = (int2*) (ws + 53402112);   // NBKT*BMAX*8 = 9,633,792 -> 63,035,904
    int2*  epair   = (int2*) (ws + 63035904);   // (E+N)*8 = 5,200,000 -> 68,235,904
    __bf16* whi1   = (__bf16*)(ws + 68235904);  // 65,536
    __bf16* wlo1   = (__bf16*)(ws + 68301440);  // 65,536
    __bf16* whi2   = (__bf16*)(ws + 68366976);  // 16,384
    __bf16* wlo2   = (__bf16*)(ws + 68383360);  // 16,384 (end 68,399,744)

    init_kernel<<<1 + (NPACK + 255) / 256, 256, 0, stream>>>(
        W1, W2, whi1, wlo1, whi2, wlo2, bcur);

    gemm1_bappend_kernel<<<NAB + GB1, 256, 0, stream>>>(
        x, whi1, wlo1, a_src1, a_dst1, h1b, als1, ald1, ei, bcur, bstage);

    bsortp1_kernel<<<NBKT, 1024, 0, stream>>>(bcur, bstage, als1, ald1, rowp, epair, p1);

    aggr1g_kernel<<<N_NODES / 16, 256, 0, stream>>>(
        rowp, epair, p1, h1b, b1, whi2, wlo2, a_src2, a_dst2, g, als2, ald2);

    aggr2_kernel<<<N_NODES / 4, 256, 0, stream>>>(rowp, epair, als2, ald2, g, b2, out);
}